// Round 4
// baseline (962.703 us; speedup 1.0000x reference)
//
#include <hip/hip_runtime.h>

#define D 16
#define ATTN_SLOPE 0.2f
#define ACT_SLOPE 0.01f

// feat_src[n][d] = sum_k h[n][k]*Wsrc[k][d] + bsrc[d]; same for dst.
__global__ void node_transform_kernel(const float* __restrict__ h,
                                      const float* __restrict__ Wsrc,
                                      const float* __restrict__ bsrc,
                                      const float* __restrict__ Wdst,
                                      const float* __restrict__ bdst,
                                      float* __restrict__ feat_src,
                                      float* __restrict__ feat_dst,
                                      int N) {
    __shared__ float sWs[D * D], sWd[D * D], sbs[D], sbd[D];
    int t = threadIdx.x;
    if (t < D * D) {
        sWs[t] = Wsrc[t];
        sWd[t] = Wdst[t];
    }
    if (t < D) {
        sbs[t] = bsrc[t];
        sbd[t] = bdst[t];
    }
    __syncthreads();
    int n = blockIdx.x * blockDim.x + t;
    if (n >= N) return;
    float hv[D];
#pragma unroll
    for (int k = 0; k < D; k++) hv[k] = h[n * D + k];
#pragma unroll
    for (int d = 0; d < D; d++) {
        float ss = sbs[d];
        float sd = sbd[d];
#pragma unroll
        for (int k = 0; k < D; k++) {
            ss += hv[k] * sWs[k * D + d];
            sd += hv[k] * sWd[k * D + d];
        }
        feat_src[n * D + d] = ss;
        feat_dst[n * D + d] = sd;
    }
}

__global__ void hist_kernel(const int* __restrict__ dst, int* __restrict__ deg, int E) {
    int e = blockIdx.x * blockDim.x + threadIdx.x;
    if (e < E) atomicAdd(&deg[dst[e]], 1);
}

// per-256-block exclusive scan; block sums out. NB = ceil(N/256) must be <= 512.
__global__ void scan_blocks_kernel(const int* __restrict__ deg, int* __restrict__ part,
                                   int* __restrict__ bsums, int N) {
    __shared__ int tmp[256];
    int tid = threadIdx.x;
    int i = blockIdx.x * 256 + tid;
    int v = (i < N) ? deg[i] : 0;
    int x = v;
    tmp[tid] = x;
    __syncthreads();
    for (int ofs = 1; ofs < 256; ofs <<= 1) {
        int y = (tid >= ofs) ? tmp[tid - ofs] : 0;
        __syncthreads();
        x += y;
        tmp[tid] = x;
        __syncthreads();
    }
    if (i < N) part[i] = x - v;  // exclusive within block
    if (tid == 255) bsums[blockIdx.x] = x;
}

__global__ void scan_bsums_kernel(int* __restrict__ bsums, int NB) {
    __shared__ int tmp[512];
    int tid = threadIdx.x;
    int v = (tid < NB) ? bsums[tid] : 0;
    int x = v;
    tmp[tid] = x;
    __syncthreads();
    for (int ofs = 1; ofs < 512; ofs <<= 1) {
        int y = (tid >= ofs) ? tmp[tid - ofs] : 0;
        __syncthreads();
        x += y;
        tmp[tid] = x;
        __syncthreads();
    }
    if (tid < NB) bsums[tid] = x - v;  // exclusive block offsets
}

__global__ void scatter_kernel(const int* __restrict__ src, const int* __restrict__ dst,
                               const int* __restrict__ part, const int* __restrict__ bsums,
                               int* __restrict__ cur, int* __restrict__ perm_src, int E) {
    int e = blockIdx.x * blockDim.x + threadIdx.x;
    if (e >= E) return;
    int dv = dst[e];
    int pos = part[dv] + bsums[dv >> 8] + atomicAdd(&cur[dv], 1);
    perm_src[pos] = src[e];
}

// One 64-lane wave per destination node, 4 edges in flight (lane = 16*slot + d).
// Register-accumulated segmented softmax-weighted sum; finalize fused.
__global__ void gather_kernel(const int* __restrict__ perm_src,
                              const int* __restrict__ part, const int* __restrict__ bsums,
                              const int* __restrict__ deg,
                              const float* __restrict__ feat_src,
                              const float* __restrict__ feat_dst,
                              const float* __restrict__ attn,
                              float* __restrict__ out, int N) {
    int tid = threadIdx.x;
    int wave = tid >> 6;
    int lane = tid & 63;
    int sub = lane >> 4;
    int d = lane & 15;
    int n = blockIdx.x * 4 + wave;
    if (n >= N) return;
    int off = part[n] + bsums[n >> 8];
    int end = off + deg[n];
    float fd = feat_dst[n * D + d];
    float ad = attn[d];
    float acc = 0.f, den = 0.f;
    for (int j = off + sub; j < end; j += 4) {
        int s = perm_src[j];
        float el = feat_src[s * D + d];
        float v = el + fd;
        v = v > 0.f ? v : ATTN_SLOPE * v;
        float p = v * ad;
        p += __shfl_xor(p, 1, 16);
        p += __shfl_xor(p, 2, 16);
        p += __shfl_xor(p, 4, 16);
        p += __shfl_xor(p, 8, 16);
        float ex = __expf(p);
        acc += ex * el;
        den += ex;
    }
    // combine the 4 edge slots
    acc += __shfl_xor(acc, 16, 64);
    acc += __shfl_xor(acc, 32, 64);
    den += __shfl_xor(den, 16, 64);
    den += __shfl_xor(den, 32, 64);
    if (sub == 0) {
        float v = den > 0.f ? acc / den : 0.f;
        v = v > 0.f ? v : ACT_SLOPE * v;
        out[n * D + d] = v;
    }
}

static void run_layer(const float* h, const int* src, const int* dst,
                      const float* Wsrc, const float* bsrc,
                      const float* Wdst, const float* bdst, const float* attn,
                      float* feat_src, float* feat_dst,
                      int* deg, int* cur, int* part, int* bsums, int* perm_src,
                      float* out, int N, int E, hipStream_t stream) {
    const int BLK = 256;
    const int NB = (N + 255) / 256;

    hipMemsetAsync(deg, 0, (size_t)N * 2 * sizeof(int), stream);  // deg + cur contiguous

    node_transform_kernel<<<(N + BLK - 1) / BLK, BLK, 0, stream>>>(
        h, Wsrc, bsrc, Wdst, bdst, feat_src, feat_dst, N);

    hist_kernel<<<(E + BLK - 1) / BLK, BLK, 0, stream>>>(dst, deg, E);
    scan_blocks_kernel<<<NB, 256, 0, stream>>>(deg, part, bsums, N);
    scan_bsums_kernel<<<1, 512, 0, stream>>>(bsums, NB);
    scatter_kernel<<<(E + BLK - 1) / BLK, BLK, 0, stream>>>(
        src, dst, part, bsums, cur, perm_src, E);

    gather_kernel<<<(N + 3) / 4, 256, 0, stream>>>(
        perm_src, part, bsums, deg, feat_src, feat_dst, attn, out, N);
}

extern "C" void kernel_launch(void* const* d_in, const int* in_sizes, int n_in,
                              void* d_out, int out_size, void* d_ws, size_t ws_size,
                              hipStream_t stream) {
    const float* emb = (const float*)d_in[0];
    const int* src1 = (const int*)d_in[1];
    const int* dst1 = (const int*)d_in[2];
    const int* src2 = (const int*)d_in[3];
    const int* dst2 = (const int*)d_in[4];
    const float* Wsrc1 = (const float*)d_in[5];
    const float* bsrc1 = (const float*)d_in[6];
    const float* Wdst1 = (const float*)d_in[7];
    const float* bdst1 = (const float*)d_in[8];
    const float* attn1 = (const float*)d_in[9];
    const float* Wsrc2 = (const float*)d_in[10];
    const float* bsrc2 = (const float*)d_in[11];
    const float* Wdst2 = (const float*)d_in[12];
    const float* bdst2 = (const float*)d_in[13];
    const float* attn2 = (const float*)d_in[14];

    const int N = in_sizes[0] / D;
    const int E1 = in_sizes[1];
    const int E2 = in_sizes[3];
    const int Emax = E1 > E2 ? E1 : E2;

    float* ws = (float*)d_ws;
    float* feat_src = ws;                        // N*D
    float* feat_dst = feat_src + (size_t)N * D;  // N*D
    float* h2 = feat_dst + (size_t)N * D;        // N*D
    int* deg = (int*)(h2 + (size_t)N * D);       // N
    int* cur = deg + N;                          // N  (contiguous with deg for one memset)
    int* part = cur + N;                         // N
    int* bsums = part + N;                       // 512
    int* perm_src = bsums + 512;                 // Emax
    (void)ws_size; (void)n_in; (void)out_size;

    run_layer(emb, src1, dst1, Wsrc1, bsrc1, Wdst1, bdst1, attn1,
              feat_src, feat_dst, deg, cur, part, bsums, perm_src,
              h2, N, E1, stream);

    run_layer(h2, src2, dst2, Wsrc2, bsrc2, Wdst2, bdst2, attn2,
              feat_src, feat_dst, deg, cur, part, bsums, perm_src,
              (float*)d_out, N, E2, stream);
}